// Round 9
// baseline (418.896 us; speedup 1.0000x reference)
//
#include <hip/hip_runtime.h>
#include <hip/hip_bf16.h>
#include <math.h>

typedef __bf16 bf16;
typedef bf16 bf16x8 __attribute__((ext_vector_type(8)));
typedef bf16 bf16x4v __attribute__((ext_vector_type(4)));
typedef float f32x4 __attribute__((ext_vector_type(4)));

#define GLD16(g, l) __builtin_amdgcn_global_load_lds(                          \
    (__attribute__((address_space(1))) void*)(g),                              \
    (__attribute__((address_space(3))) void*)(l), 16, 0, 0)

#define MFMA16(a, b, c) __builtin_amdgcn_mfma_f32_16x16x32_bf16((a), (b), (c), 0, 0, 0)

#if __has_builtin(__builtin_amdgcn_exp2f)
#define EXP2F(x) __builtin_amdgcn_exp2f(x)
#else
#define EXP2F(x) exp2f(x)
#endif

__device__ __forceinline__ f32x4 shfl_xor4(f32x4 a, int m) {
  f32x4 r;
  #pragma unroll
  for (int i = 0; i < 4; i++) r[i] = __shfl_xor(a[i], m);
  return r;
}

// ---------------- fused prep: cast x->bf16 + 4 weight transposes in ONE launch ----------------
// (verified R6/R8: absmax unchanged)
__global__ __launch_bounds__(256) void prep(const float* __restrict__ x,
                                            const float* __restrict__ Wq,
                                            const float* __restrict__ Wk,
                                            const float* __restrict__ Wv,
                                            const float* __restrict__ Wo,
                                            bf16* __restrict__ Xb,
                                            bf16* __restrict__ Wqkvt,
                                            bf16* __restrict__ Wot,
                                            float qscale) {
  const int id = blockIdx.x;
  const int tid = threadIdx.x;
  if (id >= 10240) {  // vector cast
    int i = (id - 10240) * 256 + tid;
    float4 v = ((const float4*)x)[i];
    bf16x4v o;
    o.x = (bf16)v.x; o.y = (bf16)v.y; o.z = (bf16)v.z; o.w = (bf16)v.w;
    ((bf16x4v*)Xb)[i] = o;
    return;
  }
  __shared__ float t[32][33];
  const float* in; bf16* out; int colsIn, outRowOff, bx, by; float scale;
  if (id < 4096)      { in = Wq; out = Wqkvt; colsIn = 2048; outRowOff = 0;    scale = qscale; bx = id & 63;          by = id >> 6; }
  else if (id < 5120) { in = Wk; out = Wqkvt; colsIn = 512;  outRowOff = 2048; scale = 1.0f;   bx = (id - 4096) & 15; by = (id - 4096) >> 4; }
  else if (id < 6144) { in = Wv; out = Wqkvt; colsIn = 512;  outRowOff = 2560; scale = 1.0f;   bx = (id - 5120) & 15; by = (id - 5120) >> 4; }
  else                { in = Wo; out = Wot;   colsIn = 2048; outRowOff = 0;    scale = 1.0f;   bx = (id - 6144) & 63; by = (id - 6144) >> 6; }
  const int c0 = bx * 32, r0 = by * 32;
  const int tx = tid & 31, ty = tid >> 5;
  #pragma unroll
  for (int i = 0; i < 32; i += 8)
    t[ty + i][tx] = in[(size_t)(r0 + ty + i) * colsIn + (c0 + tx)];
  __syncthreads();
  #pragma unroll
  for (int i = 0; i < 32; i += 8)
    out[(size_t)(outRowOff + c0 + ty + i) * 2048 + (r0 + tx)] = (bf16)(t[tx][ty + i] * scale);
}

// ---------------- m97-style GEMM: A[M][K] bf16, Bt[N][K] bf16 -> C[M][N] ----------------
// One-tile-per-block, 3 blocks/CU co-resident (verified R8).
// Vg!=nullptr => V col-tiles (colBase>=2560) write transposed bf16 directly to Vg[d][n]
// and skip the never-read QKV V-region (replaces transpose_v kernel; verified R6/R8).
template <typename OutT>
__global__ __launch_bounds__(256, 2) void gemm_bt(const bf16* __restrict__ A,
                                                  const bf16* __restrict__ Bt,
                                                  OutT* __restrict__ C,
                                                  bf16* __restrict__ Vg,
                                                  int N, int K) {
  __shared__ __attribute__((aligned(16))) bf16 As[128 * 32];
  __shared__ __attribute__((aligned(16))) bf16 Bs[128 * 32];
  const int tid = threadIdx.x;
  const int lane = tid & 63;
  const int wave = tid >> 6;
  const int wm = wave >> 1, wn = wave & 1;
  const int l15 = lane & 15, quad = lane >> 4;
  const int rowBase = blockIdx.y * 128;
  const int colBase = blockIdx.x * 128;

  f32x4 acc[4][4] = {};

  const int cb0 = wave * 64;
  const int c0 = cb0 + lane;
  const int c1 = c0 + 256;
  const bf16* a0 = A + (size_t)(rowBase + (c0 >> 2)) * K + (c0 & 3) * 8;
  const bf16* a1 = A + (size_t)(rowBase + (c1 >> 2)) * K + (c1 & 3) * 8;
  const bf16* b0 = Bt + (size_t)(colBase + (c0 >> 2)) * K + (c0 & 3) * 8;
  const bf16* b1 = Bt + (size_t)(colBase + (c1 >> 2)) * K + (c1 & 3) * 8;
  bf16* lA0 = &As[cb0 * 8];
  bf16* lA1 = &As[(cb0 + 256) * 8];
  bf16* lB0 = &Bs[cb0 * 8];
  bf16* lB1 = &Bs[(cb0 + 256) * 8];

  for (int k0 = 0; k0 < K; k0 += 32) {
    GLD16(a0 + k0, lA0);
    GLD16(a1 + k0, lA1);
    GLD16(b0 + k0, lB0);
    GLD16(b1 + k0, lB1);
    __syncthreads();
    bf16x8 af[4], bfr[4];
    #pragma unroll
    for (int i = 0; i < 4; i++)
      af[i] = *(const bf16x8*)&As[(wm * 64 + i * 16 + l15) * 32 + quad * 8];
    #pragma unroll
    for (int i = 0; i < 4; i++)
      bfr[i] = *(const bf16x8*)&Bs[(wn * 64 + i * 16 + l15) * 32 + quad * 8];
    #pragma unroll
    for (int i = 0; i < 4; i++)
      #pragma unroll
      for (int j = 0; j < 4; j++)
        acc[i][j] = MFMA16(af[i], bfr[j], acc[i][j]);
    __syncthreads();
  }

  if (Vg != nullptr && colBase >= 2560) {
    // transposed V write: Vg[(b*4+kvh)*128 + d][n] = acc
    const int kvh = (colBase - 2560) >> 7;
    #pragma unroll
    for (int i = 0; i < 4; i++) {
      int row = rowBase + wm * 64 + i * 16 + quad * 4;
      int bb = row >> 11;
      int n0 = row & 2047;
      #pragma unroll
      for (int j = 0; j < 4; j++) {
        int d = wn * 64 + j * 16 + l15;
        bf16x4v o;
        #pragma unroll
        for (int r = 0; r < 4; r++) o[r] = (bf16)acc[i][j][r];
        *(bf16x4v*)&Vg[((size_t)(bb * 4 + kvh) * 128 + d) * 2048 + n0] = o;
      }
    }
  } else {
    #pragma unroll
    for (int i = 0; i < 4; i++) {
      int row = rowBase + wm * 64 + i * 16 + quad * 4;
      #pragma unroll
      for (int j = 0; j < 4; j++) {
        int col = colBase + wn * 64 + j * 16 + l15;
        #pragma unroll
        for (int r = 0; r < 4; r++)
          C[(size_t)(row + r) * N + col] = (OutT)acc[i][j][r];
      }
    }
  }
}

// ---------------- flash-style GQA attention v8: NO K/V LDS staging ----------------
// R8 post-mortem insight: kf/vf addresses are wave-independent -- all 4 waves read the
// SAME K/V fragments, so the LDS round-trip (GLD16 + vmcnt-drain barrier + swizzled
// ds_read) only re-creates what L1 broadcast provides for free. K/V per (b,kvh) are
// 512KB each (L2-resident); fragment reads coalesce as 16 rows x contiguous 64B.
// v8 reads K/V fragments DIRECTLY from global (catalog m169: dropping V-staging at
// L2-fit sizes was +26%). The k-loop now has NO barriers at all (Pl is per-wave);
// LDS = Pl only (17.4KB) -> more blocks/CU; masked waves break out early.
// Split-K + balanced BMAP + ones-column l + defer-max unchanged (verified R5/R8).
#define MASKV (-1e30f)

// entry code = qt*4 + split*2 + half. CU c gets entries {c>>5, (c>>5)+8, (c>>5)+16}:
// every group of 3 sums to 34 tiles; longest block 20 tiles.
__device__ const unsigned char BMAP[22] = {
  28, 58, 24, 50, 20, 46, 36, 32,      // e0..e7:  qt7f qt14h0 qt6f qt12h0 qt5f qt11h0 qt9f qt8f
  62, 59, 54, 51, 47, 42, 55, 63,      // e8..e15: qt15h0 qt14h1 qt13h0 qt12h1 qt11h1 qt10h0 qt13h1 qt15h1
  0, 4, 8, 12, 16, 43                  // e16..e21: qt0f qt1f qt2f qt3f qt4f qt10h1
};

#define SLOT_F32 16640  // 128*128 Oacc + 128 m + 128 l

__global__ __launch_bounds__(256, 2) void gqa_attn(const bf16* __restrict__ QKV,
                                                   const bf16* __restrict__ Vg,
                                                   bf16* __restrict__ Obf,
                                                   float* __restrict__ Part) {
  __shared__ __attribute__((aligned(16))) bf16 Pl[4][32 * 68]; // per-wave P, stride 68

  const int tid = threadIdx.x;
  const int lane = tid & 63;
  const int wave = tid >> 6;
  const int l15 = lane & 15, quad = lane >> 4;

  const int e = BMAP[blockIdx.x >> 5];
  const int bh = blockIdx.x & 31;
  const int qt = e >> 2;
  const int split = (e >> 1) & 1;
  const int half = e & 1;
  const int b = bh >> 4, h = bh & 15, kvh = h >> 2;
  const int q0 = qt * 128;
  const int nkt = 2 * qt + 2;
  const int kt_lo = (split && half) ? (nkt >> 1) : 0;
  const int kt_hi = (split && !half) ? (nkt >> 1) : nkt;

  const size_t rs = 3072;
  const bf16* Qb  = QKV + (size_t)b * 2048 * rs + h * 128;
  const bf16* Kb  = QKV + (size_t)b * 2048 * rs + 2048 + kvh * 128;
  const bf16* Vgb = Vg + (size_t)(b * 4 + kvh) * 128 * 2048;

  // Q fragments (already scaled): wave owns rows [q0+wave*32, +32)
  bf16x8 qf[2][4];
  #pragma unroll
  for (int mt = 0; mt < 2; mt++) {
    int row = q0 + wave * 32 + mt * 16 + l15;
    #pragma unroll
    for (int ks = 0; ks < 4; ks++)
      qf[mt][ks] = *(const bf16x8*)&Qb[(size_t)row * rs + ks * 32 + quad * 8];
  }

  // constant all-ones B-fragment for the l-accumulator MFMA
  bf16x8 ones8;
  #pragma unroll
  for (int i = 0; i < 8; i++) ones8[i] = (bf16)1.0f;

  f32x4 oacc[2][8] = {};
  f32x4 lacc[2] = {};
  f32x4 mrow[2];
  #pragma unroll
  for (int mt = 0; mt < 2; mt++)
    #pragma unroll
    for (int r = 0; r < 4; r++) mrow[mt][r] = MASKV;

  const int myrow_hi = q0 + wave * 32 + 31;
  // waves never have work past their diagonal tile: truncate the loop (no barriers to hit)
  const int kt_hi_w = min(kt_hi, (myrow_hi >> 6) + 1);

  for (int kt = kt_lo; kt < kt_hi_w; kt++) {
    const int k0 = kt * 64;

    // S = Q K^T (log2 domain); K fragments straight from global (L1-broadcast across waves)
    f32x4 s[2][4] = {};
    #pragma unroll
    for (int ks = 0; ks < 4; ks++) {
      #pragma unroll
      for (int nt = 0; nt < 4; nt++) {
        bf16x8 kf = *(const bf16x8*)&Kb[(size_t)(k0 + nt * 16 + l15) * rs + (ks * 4 + quad) * 8];
        s[0][nt] = MFMA16(qf[0][ks], kf, s[0][nt]);
        s[1][nt] = MFMA16(qf[1][ks], kf, s[1][nt]);
      }
    }
    // causal mask: only the last two k-tiles can intersect the diagonal (uniform branch)
    if (kt >= nkt - 2) {
      #pragma unroll
      for (int mt = 0; mt < 2; mt++) {
        int rowb = q0 + wave * 32 + mt * 16 + quad * 4;
        #pragma unroll
        for (int nt = 0; nt < 4; nt++) {
          int col = k0 + nt * 16 + l15;
          #pragma unroll
          for (int r = 0; r < 4; r++)
            if (col > rowb + r) s[mt][nt][r] = MASKV;
        }
      }
    }
    // online softmax (log2 domain); l handled by ones-column MFMA in PV
    #pragma unroll
    for (int mt = 0; mt < 2; mt++) {
      f32x4 mx = s[mt][0];
      #pragma unroll
      for (int nt = 1; nt < 4; nt++)
        #pragma unroll
        for (int r = 0; r < 4; r++) mx[r] = fmaxf(mx[r], s[mt][nt][r]);
      #pragma unroll
      for (int d = 1; d < 16; d <<= 1) {
        f32x4 o = shfl_xor4(mx, d);
        #pragma unroll
        for (int r = 0; r < 4; r++) mx[r] = fmaxf(mx[r], o[r]);
      }
      // defer-max (T13): keep old running max while growth <= 8 (p bounded by 2^8)
      bool noresc = (mx[0] <= mrow[mt][0] + 8.f) && (mx[1] <= mrow[mt][1] + 8.f) &&
                    (mx[2] <= mrow[mt][2] + 8.f) && (mx[3] <= mrow[mt][3] + 8.f);
      if (!__all(noresc)) {
        f32x4 alpha;
        #pragma unroll
        for (int r = 0; r < 4; r++) {
          float mn = fmaxf(mrow[mt][r], mx[r]);
          alpha[r] = EXP2F(mrow[mt][r] - mn);
          mrow[mt][r] = mn;
        }
        #pragma unroll
        for (int no = 0; no < 8; no++)
          #pragma unroll
          for (int r = 0; r < 4; r++) oacc[mt][no][r] *= alpha[r];
        #pragma unroll
        for (int r = 0; r < 4; r++) lacc[mt][r] *= alpha[r];
      }
      // P = 2^(s - m): C-layout -> per-wave LDS (A-layout consumable); stride 68
      // (same-wave write->read: compiler's lgkmcnt ordering suffices, no barrier)
      #pragma unroll
      for (int nt = 0; nt < 4; nt++)
        #pragma unroll
        for (int r = 0; r < 4; r++) {
          float p = EXP2F(s[mt][nt][r] - mrow[mt][r]);
          Pl[wave][(mt * 16 + quad * 4 + r) * 68 + nt * 16 + l15] = (bf16)p;
        }
    }
    // O += P V ; l += P 1; V fragments straight from global (row-contiguous 64B/4 lanes)
    #pragma unroll
    for (int ks2 = 0; ks2 < 2; ks2++) {
      bf16x8 pf0 = *(const bf16x8*)&Pl[wave][l15 * 68 + ks2 * 32 + quad * 8];
      bf16x8 pf1 = *(const bf16x8*)&Pl[wave][(16 + l15) * 68 + ks2 * 32 + quad * 8];
      lacc[0] = MFMA16(pf0, ones8, lacc[0]);
      lacc[1] = MFMA16(pf1, ones8, lacc[1]);
      #pragma unroll
      for (int no = 0; no < 8; no++) {
        bf16x8 vf = *(const bf16x8*)&Vgb[(size_t)(no * 16 + l15) * 2048 + k0 + ks2 * 32 + quad * 8];
        oacc[0][no] = MFMA16(pf0, vf, oacc[0][no]);
        oacc[1][no] = MFMA16(pf1, vf, oacc[1][no]);
      }
    }
  }

  if (!split) {
    // epilogue: normalize and write bf16
    #pragma unroll
    for (int mt = 0; mt < 2; mt++) {
      f32x4 linv;
      #pragma unroll
      for (int r = 0; r < 4; r++) linv[r] = 1.0f / lacc[mt][r];
      int row = q0 + wave * 32 + mt * 16 + quad * 4;
      #pragma unroll
      for (int no = 0; no < 8; no++) {
        int col = h * 128 + no * 16 + l15;
        #pragma unroll
        for (int r = 0; r < 4; r++)
          Obf[(size_t)(b * 2048 + row + r) * 2048 + col] = (bf16)(oacc[mt][no][r] * linv[r]);
      }
    }
  } else {
    // write f32 partial (unnormalized Oacc + m + l); merge kernel combines after this dispatch
    const int fidx = bh * 6 + (qt - 10);
    float* slot = Part + (size_t)(fidx * 2 + half) * SLOT_F32;
    #pragma unroll
    for (int mt = 0; mt < 2; mt++) {
      int row = wave * 32 + mt * 16 + quad * 4;  // local row 0..127
      #pragma unroll
      for (int no = 0; no < 8; no++) {
        int col = no * 16 + l15;
        #pragma unroll
        for (int r = 0; r < 4; r++)
          slot[(row + r) * 128 + col] = oacc[mt][no][r];
      }
    }
    if (l15 == 0) {
      #pragma unroll
      for (int mt = 0; mt < 2; mt++)
        #pragma unroll
        for (int r = 0; r < 4; r++) {
          int row = wave * 32 + mt * 16 + quad * 4 + r;
          slot[16384 + row] = mrow[mt][r];
          slot[16512 + row] = lacc[mt][r];
        }
    }
  }
}

// ---------------- deterministic split merge: Obf rows for qt>=10 ----------------
__global__ __launch_bounds__(256) void merge_split(const float* __restrict__ Part,
                                                   bf16* __restrict__ Obf) {
  const int fidx = blockIdx.x;        // 0..191
  const int bh = fidx / 6, qt = 10 + fidx % 6;
  const int b = bh >> 4, h = bh & 15;
  const int tid = threadIdx.x;
  const int cl = (tid & 31) * 4;      // column 0..124 step 4
  const int r0 = tid >> 5;            // row stream 0..7
  const float* s0 = Part + (size_t)(fidx * 2) * SLOT_F32;
  const float* s1 = s0 + SLOT_F32;
  #pragma unroll
  for (int i = 0; i < 16; i++) {
    int row = r0 + i * 8;
    float m0 = s0[16384 + row], l0 = s0[16512 + row];
    float m1 = s1[16384 + row], l1 = s1[16512 + row];
    float ms = fmaxf(m0, m1);
    float a0 = EXP2F(m0 - ms), a1 = EXP2F(m1 - ms);
    float linv = 1.0f / (l0 * a0 + l1 * a1);
    f32x4 v0 = *(const f32x4*)&s0[row * 128 + cl];
    f32x4 v1 = *(const f32x4*)&s1[row * 128 + cl];
    bf16x4v o;
    #pragma unroll
    for (int r = 0; r < 4; r++) o[r] = (bf16)((v0[r] * a0 + v1[r] * a1) * linv);
    *(bf16x4v*)&Obf[(size_t)(b * 2048 + qt * 128 + row) * 2048 + h * 128 + cl] = o;
  }
}

extern "C" void kernel_launch(void* const* d_in, const int* in_sizes, int n_in,
                              void* d_out, int out_size, void* d_ws, size_t ws_size,
                              hipStream_t stream) {
  const float* x  = (const float*)d_in[0];
  // d_in[1] = mask: always causal tril; handled analytically.
  const float* Wq = (const float*)d_in[2];
  const float* Wk = (const float*)d_in[3];
  const float* Wv = (const float*)d_in[4];
  const float* Wo = (const float*)d_in[5];
  float* out = (float*)d_out;

  // workspace layout (bf16 elements)
  bf16* Xb    = (bf16*)d_ws;           // 4096x2048
  bf16* Wqkvt = Xb + 8388608;          // 3072x2048 (transposed, fused Q|K|V)
  bf16* Wot   = Wqkvt + 6291456;       // 2048x2048 (transposed)
  bf16* QKV   = Wot + 4194304;         // 4096x3072 (V col-range unwritten/unused)
  bf16* Obf   = QKV + 12582912;        // 4096x2048
  bf16* Vg    = Obf + 8388608;         // 8 x 128 x 2048 (V^T per (b,kvh), written by gemm1)
  // total 83,886,080 bytes

  // split-K partials overlay Xb+Wqkvt (29.36 MB dead after gemm1):
  // 384 slots x 16640 f32 = 25.56 MB.
  float* Part = (float*)d_ws;

  const float qscale = (float)(0.08838834764831845 * 1.4426950408889634);

  prep<<<18432, 256, 0, stream>>>(x, Wq, Wk, Wv, Wo, Xb, Wqkvt, Wot, qscale);
  gemm_bt<bf16><<<dim3(24, 32), 256, 0, stream>>>(Xb, Wqkvt, QKV, Vg, 3072, 2048);
  gqa_attn<<<704, 256, 0, stream>>>(QKV, Vg, Obf, Part);
  merge_split<<<192, 256, 0, stream>>>(Part, Obf);
  gemm_bt<float><<<dim3(16, 32), 256, 0, stream>>>(Obf, Wot, out, (bf16*)nullptr, 2048, 2048);
}

// Round 10
// 317.579 us; speedup vs baseline: 1.3190x; 1.3190x over previous
//
#include <hip/hip_runtime.h>
#include <hip/hip_bf16.h>
#include <math.h>

typedef __bf16 bf16;
typedef bf16 bf16x8 __attribute__((ext_vector_type(8)));
typedef bf16 bf16x4v __attribute__((ext_vector_type(4)));
typedef float f32x4 __attribute__((ext_vector_type(4)));

#define GLD16(g, l) __builtin_amdgcn_global_load_lds(                          \
    (__attribute__((address_space(1))) void*)(g),                              \
    (__attribute__((address_space(3))) void*)(l), 16, 0, 0)

#define MFMA16(a, b, c) __builtin_amdgcn_mfma_f32_16x16x32_bf16((a), (b), (c), 0, 0, 0)

#if __has_builtin(__builtin_amdgcn_exp2f)
#define EXP2F(x) __builtin_amdgcn_exp2f(x)
#else
#define EXP2F(x) exp2f(x)
#endif

__device__ __forceinline__ f32x4 shfl_xor4(f32x4 a, int m) {
  f32x4 r;
  #pragma unroll
  for (int i = 0; i < 4; i++) r[i] = __shfl_xor(a[i], m);
  return r;
}

// ---------------- fused prep: cast x->bf16 + 4 weight transposes in ONE launch ----------------
// (verified R6/R8: absmax unchanged)
__global__ __launch_bounds__(256) void prep(const float* __restrict__ x,
                                            const float* __restrict__ Wq,
                                            const float* __restrict__ Wk,
                                            const float* __restrict__ Wv,
                                            const float* __restrict__ Wo,
                                            bf16* __restrict__ Xb,
                                            bf16* __restrict__ Wqkvt,
                                            bf16* __restrict__ Wot,
                                            float qscale) {
  const int id = blockIdx.x;
  const int tid = threadIdx.x;
  if (id >= 10240) {  // vector cast
    int i = (id - 10240) * 256 + tid;
    float4 v = ((const float4*)x)[i];
    bf16x4v o;
    o.x = (bf16)v.x; o.y = (bf16)v.y; o.z = (bf16)v.z; o.w = (bf16)v.w;
    ((bf16x4v*)Xb)[i] = o;
    return;
  }
  __shared__ float t[32][33];
  const float* in; bf16* out; int colsIn, outRowOff, bx, by; float scale;
  if (id < 4096)      { in = Wq; out = Wqkvt; colsIn = 2048; outRowOff = 0;    scale = qscale; bx = id & 63;          by = id >> 6; }
  else if (id < 5120) { in = Wk; out = Wqkvt; colsIn = 512;  outRowOff = 2048; scale = 1.0f;   bx = (id - 4096) & 15; by = (id - 4096) >> 4; }
  else if (id < 6144) { in = Wv; out = Wqkvt; colsIn = 512;  outRowOff = 2560; scale = 1.0f;   bx = (id - 5120) & 15; by = (id - 5120) >> 4; }
  else                { in = Wo; out = Wot;   colsIn = 2048; outRowOff = 0;    scale = 1.0f;   bx = (id - 6144) & 63; by = (id - 6144) >> 6; }
  const int c0 = bx * 32, r0 = by * 32;
  const int tx = tid & 31, ty = tid >> 5;
  #pragma unroll
  for (int i = 0; i < 32; i += 8)
    t[ty + i][tx] = in[(size_t)(r0 + ty + i) * colsIn + (c0 + tx)];
  __syncthreads();
  #pragma unroll
  for (int i = 0; i < 32; i += 8)
    out[(size_t)(outRowOff + c0 + ty + i) * 2048 + (r0 + tx)] = (bf16)(t[tx][ty + i] * scale);
}

// ---------------- m97-style GEMM: A[M][K] bf16, Bt[N][K] bf16 -> C[M][N] ----------------
// One-tile-per-block, 3 blocks/CU co-resident (verified R8).
// Vg!=nullptr => V col-tiles (colBase>=2560) write transposed bf16 directly to Vg[d][n]
// and skip the never-read QKV V-region (replaces transpose_v kernel; verified R6/R8).
template <typename OutT>
__global__ __launch_bounds__(256, 2) void gemm_bt(const bf16* __restrict__ A,
                                                  const bf16* __restrict__ Bt,
                                                  OutT* __restrict__ C,
                                                  bf16* __restrict__ Vg,
                                                  int N, int K) {
  __shared__ __attribute__((aligned(16))) bf16 As[128 * 32];
  __shared__ __attribute__((aligned(16))) bf16 Bs[128 * 32];
  const int tid = threadIdx.x;
  const int lane = tid & 63;
  const int wave = tid >> 6;
  const int wm = wave >> 1, wn = wave & 1;
  const int l15 = lane & 15, quad = lane >> 4;
  const int rowBase = blockIdx.y * 128;
  const int colBase = blockIdx.x * 128;

  f32x4 acc[4][4] = {};

  const int cb0 = wave * 64;
  const int c0 = cb0 + lane;
  const int c1 = c0 + 256;
  const bf16* a0 = A + (size_t)(rowBase + (c0 >> 2)) * K + (c0 & 3) * 8;
  const bf16* a1 = A + (size_t)(rowBase + (c1 >> 2)) * K + (c1 & 3) * 8;
  const bf16* b0 = Bt + (size_t)(colBase + (c0 >> 2)) * K + (c0 & 3) * 8;
  const bf16* b1 = Bt + (size_t)(colBase + (c1 >> 2)) * K + (c1 & 3) * 8;
  bf16* lA0 = &As[cb0 * 8];
  bf16* lA1 = &As[(cb0 + 256) * 8];
  bf16* lB0 = &Bs[cb0 * 8];
  bf16* lB1 = &Bs[(cb0 + 256) * 8];

  for (int k0 = 0; k0 < K; k0 += 32) {
    GLD16(a0 + k0, lA0);
    GLD16(a1 + k0, lA1);
    GLD16(b0 + k0, lB0);
    GLD16(b1 + k0, lB1);
    __syncthreads();
    bf16x8 af[4], bfr[4];
    #pragma unroll
    for (int i = 0; i < 4; i++)
      af[i] = *(const bf16x8*)&As[(wm * 64 + i * 16 + l15) * 32 + quad * 8];
    #pragma unroll
    for (int i = 0; i < 4; i++)
      bfr[i] = *(const bf16x8*)&Bs[(wn * 64 + i * 16 + l15) * 32 + quad * 8];
    #pragma unroll
    for (int i = 0; i < 4; i++)
      #pragma unroll
      for (int j = 0; j < 4; j++)
        acc[i][j] = MFMA16(af[i], bfr[j], acc[i][j]);
    __syncthreads();
  }

  if (Vg != nullptr && colBase >= 2560) {
    // transposed V write: Vg[(b*4+kvh)*128 + d][n] = acc
    const int kvh = (colBase - 2560) >> 7;
    #pragma unroll
    for (int i = 0; i < 4; i++) {
      int row = rowBase + wm * 64 + i * 16 + quad * 4;
      int bb = row >> 11;
      int n0 = row & 2047;
      #pragma unroll
      for (int j = 0; j < 4; j++) {
        int d = wn * 64 + j * 16 + l15;
        bf16x4v o;
        #pragma unroll
        for (int r = 0; r < 4; r++) o[r] = (bf16)acc[i][j][r];
        *(bf16x4v*)&Vg[((size_t)(bb * 4 + kvh) * 128 + d) * 2048 + n0] = o;
      }
    }
  } else {
    #pragma unroll
    for (int i = 0; i < 4; i++) {
      int row = rowBase + wm * 64 + i * 16 + quad * 4;
      #pragma unroll
      for (int j = 0; j < 4; j++) {
        int col = colBase + wn * 64 + j * 16 + l15;
        #pragma unroll
        for (int r = 0; r < 4; r++)
          C[(size_t)(row + r) * N + col] = (OutT)acc[i][j][r];
      }
    }
  }
}

// ---------------- flash-style GQA attention v9: R8 staged structure + T5 setprio ----------------
// R9 post-mortem: direct-global K/V fragment reads are 16-row-scattered (16x 64B segments
// per instruction -> 16-way L1 request split); MfmaUtil collapsed 17.5->8.1. The GLD16+LDS
// path is the transaction-compressor -- REVERTED to R8's staged loop (verified 83.5us).
// Added T5: s_setprio(1) around QK^T and PV MFMA clusters. Blocks on a CU are desynced
// (no cross-block sync, staggered BMAP lengths) = the regime where m191 measured +4-7%.
#define MASKV (-1e30f)

// entry code = qt*4 + split*2 + half. CU c gets entries {c>>5, (c>>5)+8, (c>>5)+16}:
// every group of 3 sums to 34 tiles; longest block 20 tiles.
__device__ const unsigned char BMAP[22] = {
  28, 58, 24, 50, 20, 46, 36, 32,      // e0..e7:  qt7f qt14h0 qt6f qt12h0 qt5f qt11h0 qt9f qt8f
  62, 59, 54, 51, 47, 42, 55, 63,      // e8..e15: qt15h0 qt14h1 qt13h0 qt12h1 qt11h1 qt10h0 qt13h1 qt15h1
  0, 4, 8, 12, 16, 43                  // e16..e21: qt0f qt1f qt2f qt3f qt4f qt10h1
};

#define SLOT_F32 16640  // 128*128 Oacc + 128 m + 128 l

__global__ __launch_bounds__(256, 2) void gqa_attn(const bf16* __restrict__ QKV,
                                                   const bf16* __restrict__ Vg,
                                                   bf16* __restrict__ Obf,
                                                   float* __restrict__ Part) {
  __shared__ __attribute__((aligned(16))) bf16 Kl[64 * 128];   // [key][hd], chunk c' = c ^ (key&7)
  __shared__ __attribute__((aligned(16))) bf16 Vt[128 * 64];   // [hd][key], chunk c' = c ^ (d&7)
  __shared__ __attribute__((aligned(16))) bf16 Pl[4][32 * 68]; // per-wave P, stride 68

  const int tid = threadIdx.x;
  const int lane = tid & 63;
  const int wave = tid >> 6;
  const int l15 = lane & 15, quad = lane >> 4;

  const int e = BMAP[blockIdx.x >> 5];
  const int bh = blockIdx.x & 31;
  const int qt = e >> 2;
  const int split = (e >> 1) & 1;
  const int half = e & 1;
  const int b = bh >> 4, h = bh & 15, kvh = h >> 2;
  const int q0 = qt * 128;
  const int nkt = 2 * qt + 2;
  const int kt_lo = (split && half) ? (nkt >> 1) : 0;
  const int kt_hi = (split && !half) ? (nkt >> 1) : nkt;

  const size_t rs = 3072;
  const bf16* Qb  = QKV + (size_t)b * 2048 * rs + h * 128;
  const bf16* Kb  = QKV + (size_t)b * 2048 * rs + 2048 + kvh * 128;
  const bf16* Vgb = Vg + (size_t)(b * 4 + kvh) * 128 * 2048;

  // Q fragments (already scaled): wave owns rows [q0+wave*32, +32)
  bf16x8 qf[2][4];
  #pragma unroll
  for (int mt = 0; mt < 2; mt++) {
    int row = q0 + wave * 32 + mt * 16 + l15;
    #pragma unroll
    for (int ks = 0; ks < 4; ks++)
      qf[mt][ks] = *(const bf16x8*)&Qb[(size_t)row * rs + ks * 32 + quad * 8];
  }

  // constant all-ones B-fragment for the l-accumulator MFMA
  bf16x8 ones8;
  #pragma unroll
  for (int i = 0; i < 8; i++) ones8[i] = (bf16)1.0f;

  // DMA staging pointers: swizzle folded into per-lane GLOBAL address; LDS base wave-uniform.
  const bf16* kp[4]; const bf16* vp[4];
  bf16* kl[4]; bf16* vl[4];
  #pragma unroll
  for (int t = 0; t < 4; t++) {
    int keyl = wave * 16 + t * 4 + (lane >> 4);
    int ck = (lane & 15) ^ (4 * (t & 1) + (lane >> 4));  // (keyl&7) = 4*(t&1)+(lane>>4)
    kp[t] = Kb + (size_t)(kt_lo * 64 + keyl) * rs + ck * 8;
    kl[t] = &Kl[(wave * 16 + t * 4) * 128];
    int dl = wave * 32 + t * 8 + (lane >> 3);
    int cv = (lane & 7) ^ (lane >> 3);                   // (dl&7) = lane>>3
    vp[t] = Vgb + (size_t)dl * 2048 + kt_lo * 64 + cv * 8;
    vl[t] = &Vt[(wave * 32 + t * 8) * 64];
  }

  f32x4 oacc[2][8] = {};
  f32x4 lacc[2] = {};
  f32x4 mrow[2];
  #pragma unroll
  for (int mt = 0; mt < 2; mt++)
    #pragma unroll
    for (int r = 0; r < 4; r++) mrow[mt][r] = MASKV;

  const int myrow_hi = q0 + wave * 32 + 31;
  for (int kt = kt_lo; kt < kt_hi; kt++) {
    const int k0 = kt * 64;
    __syncthreads();  // previous tile fully consumed by all waves
    #pragma unroll
    for (int t = 0; t < 4; t++) { GLD16(kp[t], kl[t]); kp[t] += 64 * rs; }
    #pragma unroll
    for (int t = 0; t < 4; t++) { GLD16(vp[t], vl[t]); vp[t] += 64; }
    __syncthreads();  // compiler drains vmcnt before barrier -> tiles ready

    if (k0 > myrow_hi) continue;  // wave fully masked for this tile

    // S = Q K^T (log2 domain)
    f32x4 s[2][4] = {};
    __builtin_amdgcn_s_setprio(1);
    #pragma unroll
    for (int ks = 0; ks < 4; ks++) {
      #pragma unroll
      for (int nt = 0; nt < 4; nt++) {
        bf16x8 kf = *(const bf16x8*)&Kl[(nt * 16 + l15) * 128 +
                                        (((ks * 4 + quad) ^ (l15 & 7)) * 8)];
        s[0][nt] = MFMA16(qf[0][ks], kf, s[0][nt]);
        s[1][nt] = MFMA16(qf[1][ks], kf, s[1][nt]);
      }
    }
    __builtin_amdgcn_s_setprio(0);
    // causal mask: only the last two k-tiles can intersect the diagonal (uniform branch)
    if (kt >= nkt - 2) {
      #pragma unroll
      for (int mt = 0; mt < 2; mt++) {
        int rowb = q0 + wave * 32 + mt * 16 + quad * 4;
        #pragma unroll
        for (int nt = 0; nt < 4; nt++) {
          int col = k0 + nt * 16 + l15;
          #pragma unroll
          for (int r = 0; r < 4; r++)
            if (col > rowb + r) s[mt][nt][r] = MASKV;
        }
      }
    }
    // online softmax (log2 domain); l handled by ones-column MFMA in PV
    #pragma unroll
    for (int mt = 0; mt < 2; mt++) {
      f32x4 mx = s[mt][0];
      #pragma unroll
      for (int nt = 1; nt < 4; nt++)
        #pragma unroll
        for (int r = 0; r < 4; r++) mx[r] = fmaxf(mx[r], s[mt][nt][r]);
      #pragma unroll
      for (int d = 1; d < 16; d <<= 1) {
        f32x4 o = shfl_xor4(mx, d);
        #pragma unroll
        for (int r = 0; r < 4; r++) mx[r] = fmaxf(mx[r], o[r]);
      }
      // defer-max (T13): keep old running max while growth <= 8 (p bounded by 2^8)
      bool noresc = (mx[0] <= mrow[mt][0] + 8.f) && (mx[1] <= mrow[mt][1] + 8.f) &&
                    (mx[2] <= mrow[mt][2] + 8.f) && (mx[3] <= mrow[mt][3] + 8.f);
      if (!__all(noresc)) {
        f32x4 alpha;
        #pragma unroll
        for (int r = 0; r < 4; r++) {
          float mn = fmaxf(mrow[mt][r], mx[r]);
          alpha[r] = EXP2F(mrow[mt][r] - mn);
          mrow[mt][r] = mn;
        }
        #pragma unroll
        for (int no = 0; no < 8; no++)
          #pragma unroll
          for (int r = 0; r < 4; r++) oacc[mt][no][r] *= alpha[r];
        #pragma unroll
        for (int r = 0; r < 4; r++) lacc[mt][r] *= alpha[r];
      }
      // P = 2^(s - m): C-layout -> per-wave LDS (A-layout consumable); stride 68
      #pragma unroll
      for (int nt = 0; nt < 4; nt++)
        #pragma unroll
        for (int r = 0; r < 4; r++) {
          float p = EXP2F(s[mt][nt][r] - mrow[mt][r]);
          Pl[wave][(mt * 16 + quad * 4 + r) * 68 + nt * 16 + l15] = (bf16)p;
        }
    }
    // O += P V ; l += P 1 (ones-column row-sum, replaces shuffle-reduce)
    __builtin_amdgcn_s_setprio(1);
    #pragma unroll
    for (int ks2 = 0; ks2 < 2; ks2++) {
      bf16x8 pf0 = *(const bf16x8*)&Pl[wave][l15 * 68 + ks2 * 32 + quad * 8];
      bf16x8 pf1 = *(const bf16x8*)&Pl[wave][(16 + l15) * 68 + ks2 * 32 + quad * 8];
      lacc[0] = MFMA16(pf0, ones8, lacc[0]);
      lacc[1] = MFMA16(pf1, ones8, lacc[1]);
      #pragma unroll
      for (int no = 0; no < 8; no++) {
        bf16x8 vf = *(const bf16x8*)&Vt[(no * 16 + l15) * 64 +
                                        (((ks2 * 4 + quad) ^ (l15 & 7)) * 8)];
        oacc[0][no] = MFMA16(pf0, vf, oacc[0][no]);
        oacc[1][no] = MFMA16(pf1, vf, oacc[1][no]);
      }
    }
    __builtin_amdgcn_s_setprio(0);
  }

  if (!split) {
    // epilogue: normalize and write bf16
    #pragma unroll
    for (int mt = 0; mt < 2; mt++) {
      f32x4 linv;
      #pragma unroll
      for (int r = 0; r < 4; r++) linv[r] = 1.0f / lacc[mt][r];
      int row = q0 + wave * 32 + mt * 16 + quad * 4;
      #pragma unroll
      for (int no = 0; no < 8; no++) {
        int col = h * 128 + no * 16 + l15;
        #pragma unroll
        for (int r = 0; r < 4; r++)
          Obf[(size_t)(b * 2048 + row + r) * 2048 + col] = (bf16)(oacc[mt][no][r] * linv[r]);
      }
    }
  } else {
    // write f32 partial (unnormalized Oacc + m + l); merge kernel combines after this dispatch
    const int fidx = bh * 6 + (qt - 10);
    float* slot = Part + (size_t)(fidx * 2 + half) * SLOT_F32;
    #pragma unroll
    for (int mt = 0; mt < 2; mt++) {
      int row = wave * 32 + mt * 16 + quad * 4;  // local row 0..127
      #pragma unroll
      for (int no = 0; no < 8; no++) {
        int col = no * 16 + l15;
        #pragma unroll
        for (int r = 0; r < 4; r++)
          slot[(row + r) * 128 + col] = oacc[mt][no][r];
      }
    }
    if (l15 == 0) {
      #pragma unroll
      for (int mt = 0; mt < 2; mt++)
        #pragma unroll
        for (int r = 0; r < 4; r++) {
          int row = wave * 32 + mt * 16 + quad * 4 + r;
          slot[16384 + row] = mrow[mt][r];
          slot[16512 + row] = lacc[mt][r];
        }
    }
  }
}

// ---------------- deterministic split merge: Obf rows for qt>=10 ----------------
__global__ __launch_bounds__(256) void merge_split(const float* __restrict__ Part,
                                                   bf16* __restrict__ Obf) {
  const int fidx = blockIdx.x;        // 0..191
  const int bh = fidx / 6, qt = 10 + fidx % 6;
  const int b = bh >> 4, h = bh & 15;
  const int tid = threadIdx.x;
  const int cl = (tid & 31) * 4;      // column 0..124 step 4
  const int r0 = tid >> 5;            // row stream 0..7
  const float* s0 = Part + (size_t)(fidx * 2) * SLOT_F32;
  const float* s1 = s0 + SLOT_F32;
  #pragma unroll
  for (int i = 0; i < 16; i++) {
    int row = r0 + i * 8;
    float m0 = s0[16384 + row], l0 = s0[16512 + row];
    float m1 = s1[16384 + row], l1 = s1[16512 + row];
    float ms = fmaxf(m0, m1);
    float a0 = EXP2F(m0 - ms), a1 = EXP2F(m1 - ms);
    float linv = 1.0f / (l0 * a0 + l1 * a1);
    f32x4 v0 = *(const f32x4*)&s0[row * 128 + cl];
    f32x4 v1 = *(const f32x4*)&s1[row * 128 + cl];
    bf16x4v o;
    #pragma unroll
    for (int r = 0; r < 4; r++) o[r] = (bf16)((v0[r] * a0 + v1[r] * a1) * linv);
    *(bf16x4v*)&Obf[(size_t)(b * 2048 + qt * 128 + row) * 2048 + h * 128 + cl] = o;
  }
}

extern "C" void kernel_launch(void* const* d_in, const int* in_sizes, int n_in,
                              void* d_out, int out_size, void* d_ws, size_t ws_size,
                              hipStream_t stream) {
  const float* x  = (const float*)d_in[0];
  // d_in[1] = mask: always causal tril; handled analytically.
  const float* Wq = (const float*)d_in[2];
  const float* Wk = (const float*)d_in[3];
  const float* Wv = (const float*)d_in[4];
  const float* Wo = (const float*)d_in[5];
  float* out = (float*)d_out;

  // workspace layout (bf16 elements)
  bf16* Xb    = (bf16*)d_ws;           // 4096x2048
  bf16* Wqkvt = Xb + 8388608;          // 3072x2048 (transposed, fused Q|K|V)
  bf16* Wot   = Wqkvt + 6291456;       // 2048x2048 (transposed)
  bf16* QKV   = Wot + 4194304;         // 4096x3072 (V col-range unwritten/unused)
  bf16* Obf   = QKV + 12582912;        // 4096x2048
  bf16* Vg    = Obf + 8388608;         // 8 x 128 x 2048 (V^T per (b,kvh), written by gemm1)
  // total 83,886,080 bytes

  // split-K partials overlay Xb+Wqkvt (29.36 MB dead after gemm1):
  // 384 slots x 16640 f32 = 25.56 MB.
  float* Part = (float*)d_ws;

  const float qscale = (float)(0.08838834764831845 * 1.4426950408889634);

  prep<<<18432, 256, 0, stream>>>(x, Wq, Wk, Wv, Wo, Xb, Wqkvt, Wot, qscale);
  gemm_bt<bf16><<<dim3(24, 32), 256, 0, stream>>>(Xb, Wqkvt, QKV, Vg, 3072, 2048);
  gqa_attn<<<704, 256, 0, stream>>>(QKV, Vg, Obf, Part);
  merge_split<<<192, 256, 0, stream>>>(Part, Obf);
  gemm_bt<float><<<dim3(16, 32), 256, 0, stream>>>(Obf, Wot, out, (bf16*)nullptr, 2048, 2048);
}